// Round 1
// baseline (742.421 us; speedup 1.0000x reference)
//
#include <hip/hip_runtime.h>

// Problem constants (fixed by reference)
#define M_TOK 8192   // tokens
#define NF    4096   // out features
#define KF    4096   // in features

typedef __attribute__((ext_vector_type(8))) short bf16x8;  // 8 bf16 = 4 VGPRs
typedef __attribute__((ext_vector_type(4))) float f32x4;   // MFMA accumulator

// ---------- helpers ----------
__device__ __forceinline__ unsigned short f2bf(float f) {
    unsigned u = __builtin_bit_cast(unsigned, f);
    u += 0x7FFFu + ((u >> 16) & 1u);   // round-to-nearest-even
    return (unsigned short)(u >> 16);
}

__device__ __forceinline__ void load_lds16(const unsigned short* g, unsigned short* l) {
    // async global->LDS, 16B per lane; LDS dest = wave-uniform base + lane*16
    __builtin_amdgcn_global_load_lds(
        (const __attribute__((address_space(1))) unsigned int*)g,
        (__attribute__((address_space(3))) unsigned int*)l,
        16, 0, 0);
}

// ---------- preprocessing kernels ----------
__global__ void scatter_kernel(const int* __restrict__ idx, const float* __restrict__ w,
                               float* __restrict__ Wd, int nnz) {
    int t = blockIdx.x * blockDim.x + threadIdx.x;
    if (t < nnz) {
        int r = idx[t];
        int c = idx[nnz + t];
        atomicAdd(Wd + (size_t)r * KF + c, w[t]);
    }
}

__global__ void f32_to_bf16_kernel(const float* __restrict__ in, unsigned short* __restrict__ out,
                                   int n4) {
    int i = blockIdx.x * blockDim.x + threadIdx.x;
    if (i >= n4) return;
    float4 v = ((const float4*)in)[i];
    ushort4 o;
    o.x = f2bf(v.x); o.y = f2bf(v.y); o.z = f2bf(v.z); o.w = f2bf(v.w);
    ((ushort4*)out)[i] = o;
}

// ---------- GEMM: C[M,N] = A[M,K](bf16) * B[N,K]^T(bf16) + bias, fp32 out ----------
// 128x128 tile, BK=32, 256 threads = 4 waves in 2x2, each wave 64x64 via 4x4 MFMA 16x16x32
__global__ __launch_bounds__(256) void gemm_bt_bias(
    const unsigned short* __restrict__ A,   // [M_TOK][KF] bf16
    const unsigned short* __restrict__ B,   // [NF][KF] bf16 (W, row-major over out features)
    const float* __restrict__ bias,
    float* __restrict__ C)
{
    __shared__ unsigned short As[128 * 32];
    __shared__ unsigned short Bs[128 * 32];

    const int tid  = threadIdx.x;
    const int lane = tid & 63;
    const int wave = tid >> 6;
    const int wm   = wave >> 1;   // 0..1
    const int wn   = wave & 1;    // 0..1
    const int bm   = blockIdx.x;  // 0..63
    const int bn   = blockIdx.y;  // 0..31

    f32x4 acc[4][4] = {};

    // staging: each wave stages 32 rows of A and 32 rows of B (2 insts of 16 rows each)
    const int lrow   = lane >> 2;        // 0..15 row within 16-row group
    const int lchunk = (lane & 3) * 8;   // bf16-element offset (16B chunks)

    const unsigned short* gA  = A + (size_t)(bm * 128 + wave * 32 + lrow) * KF + lchunk;
    const unsigned short* gA2 = gA + (size_t)16 * KF;
    const unsigned short* gB  = B + (size_t)(bn * 128 + wave * 32 + lrow) * KF + lchunk;
    const unsigned short* gB2 = gB + (size_t)16 * KF;
    unsigned short* lA  = &As[wave * 32 * 32];
    unsigned short* lA2 = lA + 16 * 32;
    unsigned short* lB  = &Bs[wave * 32 * 32];
    unsigned short* lB2 = lB + 16 * 32;

    // fragment addressing: lane l holds [row = l&15][k = (l>>4)*8 + j]
    const int fr = lane & 15;
    const int fk = (lane >> 4) * 8;

    for (int k0 = 0; k0 < KF; k0 += 32) {
        __syncthreads();   // protect LDS from previous iteration's readers
        load_lds16(gA,  lA);
        load_lds16(gA2, lA2);
        load_lds16(gB,  lB);
        load_lds16(gB2, lB2);
        gA += 32; gA2 += 32; gB += 32; gB2 += 32;
        __syncthreads();   // drain staging (vmcnt) for all waves

        bf16x8 af[4], bfr[4];
#pragma unroll
        for (int i = 0; i < 4; ++i)
            af[i] = *(const bf16x8*)&As[(wm * 64 + i * 16 + fr) * 32 + fk];
#pragma unroll
        for (int j = 0; j < 4; ++j)
            bfr[j] = *(const bf16x8*)&Bs[(wn * 64 + j * 16 + fr) * 32 + fk];
#pragma unroll
        for (int i = 0; i < 4; ++i)
#pragma unroll
            for (int j = 0; j < 4; ++j)
                acc[i][j] = __builtin_amdgcn_mfma_f32_16x16x32_bf16(af[i], bfr[j], acc[i][j], 0, 0, 0);
    }

    // epilogue: C/D layout col = lane&15, row = (lane>>4)*4 + reg
    const int crow = bm * 128 + wm * 64;
    const int ccol = bn * 128 + wn * 64;
    const int c_l  = lane & 15;
    const int r_l  = (lane >> 4) * 4;
#pragma unroll
    for (int j = 0; j < 4; ++j) {
        int col = ccol + j * 16 + c_l;
        float bv = bias[col];
#pragma unroll
        for (int i = 0; i < 4; ++i) {
#pragma unroll
            for (int r = 0; r < 4; ++r)
                C[(size_t)(crow + i * 16 + r_l + r) * NF + col] = acc[i][j][r] + bv;
        }
    }
}

// ---------- launch ----------
extern "C" void kernel_launch(void* const* d_in, const int* in_sizes, int n_in,
                              void* d_out, int out_size, void* d_ws, size_t ws_size,
                              hipStream_t stream) {
    const float* x    = (const float*)d_in[0];
    const float* w    = (const float*)d_in[1];
    const float* bias = (const float*)d_in[2];
    const int*   idx  = (const int*)d_in[3];
    float* out = (float*)d_out;
    const int nnz = in_sizes[1];

    // Scratch layout:
    //  - W fp32 dense (64MB): reuse d_out's first 64MB (fully overwritten by GEMM later)
    //  - ws + 0      : W bf16  (32MB)
    //  - ws + 32MB   : X bf16  (64MB)
    float* Wf = out;
    unsigned short* Wb = (unsigned short*)d_ws;
    unsigned short* Xb = (unsigned short*)((char*)d_ws + (size_t)NF * KF * sizeof(unsigned short));

    // 1) zero dense W
    hipMemsetAsync(Wf, 0, (size_t)NF * KF * sizeof(float), stream);
    // 2) scatter COO (duplicates sum via atomics)
    scatter_kernel<<<(nnz + 255) / 256, 256, 0, stream>>>(idx, w, Wf, nnz);
    // 3) W fp32 -> bf16
    f32_to_bf16_kernel<<<(NF * KF / 4 + 255) / 256, 256, 0, stream>>>(Wf, Wb, NF * KF / 4);
    // 4) X fp32 -> bf16
    f32_to_bf16_kernel<<<(M_TOK * KF / 4 + 255) / 256, 256, 0, stream>>>(x, Xb, M_TOK * KF / 4);
    // 5) GEMM + bias (overwrites all of d_out)
    gemm_bt_bias<<<dim3(M_TOK / 128, NF / 128), 256, 0, stream>>>(Xb, Wb, bias, out);
}

// Round 2
// 612.934 us; speedup vs baseline: 1.2113x; 1.2113x over previous
//
#include <hip/hip_runtime.h>

// Problem constants (fixed by reference)
#define M_TOK 8192   // tokens
#define NF    4096   // out features
#define KF    4096   // in features
#define BK    64     // K-tile: 64 bf16 = 128 B LDS row = full 32-bank wrap

typedef __attribute__((ext_vector_type(8))) short bf16x8;  // 8 bf16 = 4 VGPRs
typedef __attribute__((ext_vector_type(4))) float f32x4;   // MFMA accumulator

// ---------- helpers ----------
__device__ __forceinline__ unsigned short f2bf(float f) {
    unsigned u = __builtin_bit_cast(unsigned, f);
    u += 0x7FFFu + ((u >> 16) & 1u);   // round-to-nearest-even
    return (unsigned short)(u >> 16);
}

__device__ __forceinline__ void load_lds16(const unsigned short* g, unsigned short* l) {
    // async global->LDS DMA: LDS dest = wave-uniform base + lane*16 (writes conflict-free)
    __builtin_amdgcn_global_load_lds(
        (const __attribute__((address_space(1))) unsigned int*)g,
        (__attribute__((address_space(3))) unsigned int*)l,
        16, 0, 0);
}

// ---------- preprocessing ----------
// Fused: zero dense-W scratch (fp32, lives in d_out) + convert X fp32->bf16.
__global__ void prep_zero_convx(const float4* __restrict__ X, ushort4* __restrict__ Xb,
                                float4* __restrict__ Wf, int nx4, int nw4) {
    int i = blockIdx.x * blockDim.x + threadIdx.x;
    if (i < nw4) Wf[i] = (float4){0.f, 0.f, 0.f, 0.f};
    if (i < nx4) {
        float4 v = X[i];
        ushort4 o;
        o.x = f2bf(v.x); o.y = f2bf(v.y); o.z = f2bf(v.z); o.w = f2bf(v.w);
        Xb[i] = o;
    }
}

__global__ void scatter_kernel(const int* __restrict__ idx, const float* __restrict__ w,
                               float* __restrict__ Wd, int nnz) {
    int t = blockIdx.x * blockDim.x + threadIdx.x;
    if (t < nnz) {
        int r = idx[t];
        int c = idx[nnz + t];
        atomicAdd(Wd + (size_t)r * KF + c, w[t]);
    }
}

__global__ void conv_w_kernel(const float4* __restrict__ in, ushort4* __restrict__ out, int n4) {
    int i = blockIdx.x * blockDim.x + threadIdx.x;
    if (i >= n4) return;
    float4 v = in[i];
    ushort4 o;
    o.x = f2bf(v.x); o.y = f2bf(v.y); o.z = f2bf(v.z); o.w = f2bf(v.w);
    out[i] = o;
}

// ---------- GEMM: C[M,N] = A[M,K](bf16) * B[N,K]^T(bf16) + bias, fp32 out ----------
// 128x128 tile, BK=64, 256 threads = 4 waves in 2x2, each wave 64x64 via 4x4 MFMA 16x16x32.
// LDS layout: tile row r (0..127) occupies 128 B; 16B chunk c of the row is stored at
// position c ^ (r&7)  -> fragment reads are 2-way bank-aliased (free), staging DMA linear.
__global__ __launch_bounds__(256) void gemm_bt_bias(
    const unsigned short* __restrict__ A,   // [M_TOK][KF] bf16
    const unsigned short* __restrict__ B,   // [NF][KF] bf16
    const float* __restrict__ bias,
    float* __restrict__ C)
{
    __shared__ unsigned short As[128 * BK];   // 16 KB
    __shared__ unsigned short Bs[128 * BK];   // 16 KB

    const int tid  = threadIdx.x;
    const int lane = tid & 63;
    const int wave = tid >> 6;
    const int wm   = wave >> 1;   // 0..1
    const int wn   = wave & 1;    // 0..1
    const int bm   = blockIdx.x;  // 0..63
    const int bn   = blockIdx.y;  // 0..31

    f32x4 acc[4][4] = {};

    // ---- staging addressing (each wave stages 32 rows of A and B via 4 instrs of 8 rows) ----
    const int lr8 = lane >> 3;          // row within 8-row group (0..7)
    const int lp  = lane & 7;           // LDS chunk position within 128B row
    const int gc  = lp ^ lr8;           // swizzle: global chunk fetched into position lp
                                        // (r&7 == lr8 for all 4 instrs since bases are x8)

    const unsigned short* gA[4];
    const unsigned short* gB[4];
#pragma unroll
    for (int t = 0; t < 4; ++t) {
        int r = wave * 32 + t * 8 + lr8;            // tile-local row
        gA[t] = A + (size_t)(bm * 128 + r) * KF + gc * 8;
        gB[t] = B + (size_t)(bn * 128 + r) * KF + gc * 8;
    }
    unsigned short* lA[4];
    unsigned short* lB[4];
#pragma unroll
    for (int t = 0; t < 4; ++t) {
        lA[t] = &As[(wave * 32 + t * 8) * BK];
        lB[t] = &Bs[(wave * 32 + t * 8) * BK];
    }

    // ---- fragment read offsets (constant through the K loop) ----
    // A-frag for 16x16x32 MFMA: lane holds [m = lane&15][k = (lane>>4)*8 + j]
    const int fr   = lane & 15;
    const int quad = lane >> 4;
    int offA[4][2], offB[4][2];
#pragma unroll
    for (int i = 0; i < 4; ++i) {
        int rA = wm * 64 + i * 16 + fr;
        int rB = wn * 64 + i * 16 + fr;
#pragma unroll
        for (int s = 0; s < 2; ++s) {
            int c = s * 4 + quad;                       // 16B chunk index within row
            offA[i][s] = rA * BK + ((c ^ (rA & 7)) * 8);
            offB[i][s] = rB * BK + ((c ^ (rB & 7)) * 8);
        }
    }

    for (int k0 = 0; k0 < KF; k0 += BK) {
        __syncthreads();   // protect LDS from previous iteration's readers
#pragma unroll
        for (int t = 0; t < 4; ++t) load_lds16(gA[t], lA[t]);
#pragma unroll
        for (int t = 0; t < 4; ++t) load_lds16(gB[t], lB[t]);
#pragma unroll
        for (int t = 0; t < 4; ++t) { gA[t] += BK; gB[t] += BK; }
        __syncthreads();   // drain staging for all waves

#pragma unroll
        for (int s = 0; s < 2; ++s) {
            bf16x8 af[4], bfr[4];
#pragma unroll
            for (int i = 0; i < 4; ++i) af[i]  = *(const bf16x8*)&As[offA[i][s]];
#pragma unroll
            for (int j = 0; j < 4; ++j) bfr[j] = *(const bf16x8*)&Bs[offB[j][s]];
#pragma unroll
            for (int i = 0; i < 4; ++i)
#pragma unroll
                for (int j = 0; j < 4; ++j)
                    acc[i][j] = __builtin_amdgcn_mfma_f32_16x16x32_bf16(af[i], bfr[j], acc[i][j], 0, 0, 0);
        }
    }

    // epilogue: C/D layout col = lane&15, row = (lane>>4)*4 + reg
    const int crow = bm * 128 + wm * 64;
    const int ccol = bn * 128 + wn * 64;
    const int c_l  = lane & 15;
    const int r_l  = (lane >> 4) * 4;
#pragma unroll
    for (int j = 0; j < 4; ++j) {
        int col = ccol + j * 16 + c_l;
        float bv = bias[col];
#pragma unroll
        for (int i = 0; i < 4; ++i) {
#pragma unroll
            for (int r = 0; r < 4; ++r)
                C[(size_t)(crow + i * 16 + r_l + r) * NF + col] = acc[i][j][r] + bv;
        }
    }
}

// ---------- launch ----------
extern "C" void kernel_launch(void* const* d_in, const int* in_sizes, int n_in,
                              void* d_out, int out_size, void* d_ws, size_t ws_size,
                              hipStream_t stream) {
    const float* x    = (const float*)d_in[0];
    const float* w    = (const float*)d_in[1];
    const float* bias = (const float*)d_in[2];
    const int*   idx  = (const int*)d_in[3];
    float* out = (float*)d_out;
    const int nnz = in_sizes[1];

    // Scratch layout:
    //  - W fp32 dense (64MB): reuse d_out's first 64MB (fully overwritten by GEMM later)
    //  - ws + 0      : W bf16  (32MB)
    //  - ws + 32MB   : X bf16  (64MB)
    float* Wf = out;
    unsigned short* Wb = (unsigned short*)d_ws;
    unsigned short* Xb = (unsigned short*)((char*)d_ws + (size_t)NF * KF * sizeof(unsigned short));

    const int nx4 = M_TOK * KF / 4;   // 8.39M float4 of X
    const int nw4 = NF * KF / 4;      // 4.19M float4 of W scratch

    // 1) fused: zero dense W + convert X -> bf16
    prep_zero_convx<<<(nx4 + 255) / 256, 256, 0, stream>>>(
        (const float4*)x, (ushort4*)Xb, (float4*)Wf, nx4, nw4);
    // 2) scatter COO (duplicates sum via fp32 atomics)
    scatter_kernel<<<(nnz + 255) / 256, 256, 0, stream>>>(idx, w, Wf, nnz);
    // 3) W fp32 -> bf16
    conv_w_kernel<<<(nw4 + 255) / 256, 256, 0, stream>>>((const float4*)Wf, (ushort4*)Wb, nw4);
    // 4) GEMM + bias (overwrites all of d_out)
    gemm_bt_bias<<<dim3(M_TOK / 128, NF / 128), 256, 0, stream>>>(Xb, Wb, bias, out);
}

// Round 3
// 596.576 us; speedup vs baseline: 1.2445x; 1.0274x over previous
//
#include <hip/hip_runtime.h>

// Problem constants (fixed by reference)
#define M_TOK 8192   // tokens
#define NF    4096   // out features
#define KF    4096   // in features
#define BK    64     // K-tile: 64 bf16 = 128 B LDS row = full 32-bank wrap

typedef __attribute__((ext_vector_type(8))) short bf16x8;  // 8 bf16 = 4 VGPRs
typedef __attribute__((ext_vector_type(4))) float f32x4;   // MFMA accumulator
typedef __attribute__((ext_vector_type(2))) short s16x2;   // packed bf16 pair

// ---------- helpers ----------
__device__ __forceinline__ unsigned short f2bf(float f) {
    unsigned u = __builtin_bit_cast(unsigned, f);
    u += 0x7FFFu + ((u >> 16) & 1u);   // round-to-nearest-even
    return (unsigned short)(u >> 16);
}

__device__ __forceinline__ float bf2f(unsigned short b) {
    unsigned u = ((unsigned)b) << 16;
    return __builtin_bit_cast(float, u);
}

__device__ __forceinline__ void load_lds16(const unsigned short* g, unsigned short* l) {
    // async global->LDS DMA: LDS dest = wave-uniform base + lane*16 (writes conflict-free)
    __builtin_amdgcn_global_load_lds(
        (const __attribute__((address_space(1))) unsigned int*)g,
        (__attribute__((address_space(3))) unsigned int*)l,
        16, 0, 0);
}

// ---------- preprocessing ----------
// Fused: zero bf16 dense-W scratch + convert X fp32->bf16. One HBM-bound pass.
__global__ void prep_zero_convx(const float4* __restrict__ X, ushort4* __restrict__ Xb,
                                uint4* __restrict__ Wb, int nx4, int nwb) {
    int i = blockIdx.x * blockDim.x + threadIdx.x;
    if (i < nwb) Wb[i] = (uint4){0u, 0u, 0u, 0u};
    if (i < nx4) {
        float4 v = X[i];
        ushort4 o;
        o.x = f2bf(v.x); o.y = f2bf(v.y); o.z = f2bf(v.z); o.w = f2bf(v.w);
        Xb[i] = o;
    }
}

// Scatter COO directly into bf16 dense W. Duplicates sum atomically.
__global__ void scatter_bf16(const int* __restrict__ idx, const float* __restrict__ w,
                             unsigned short* __restrict__ Wb, int nnz) {
    int t = blockIdx.x * blockDim.x + threadIdx.x;
    if (t >= nnz) return;
    int r = idx[t];
    int c = idx[nnz + t];
    size_t elem = (size_t)r * KF + c;
#if __has_builtin(__builtin_amdgcn_global_atomic_fadd_v2bf16)
    unsigned short wb = f2bf(w[t]);
    s16x2 val;
    if (elem & 1) { val[0] = 0; val[1] = (short)wb; }
    else          { val[0] = (short)wb; val[1] = 0; }
    // packed bf16 atomic add; the +0.0 half is an exact no-op
    __builtin_amdgcn_global_atomic_fadd_v2bf16(
        (__attribute__((address_space(1))) s16x2*)(Wb + (elem & ~(size_t)1)), val);
#else
    // CAS fallback on the containing 32-bit word
    unsigned* addr = (unsigned*)(Wb + (elem & ~(size_t)1));
    float wf = w[t];
    unsigned old = __hip_atomic_load(addr, __ATOMIC_RELAXED, __HIP_MEMORY_SCOPE_AGENT), assumed;
    do {
        assumed = old;
        unsigned short cur = (elem & 1) ? (unsigned short)(assumed >> 16)
                                        : (unsigned short)(assumed & 0xffffu);
        unsigned short nw = f2bf(bf2f(cur) + wf);
        unsigned newv = (elem & 1) ? ((assumed & 0x0000ffffu) | ((unsigned)nw << 16))
                                   : ((assumed & 0xffff0000u) | (unsigned)nw);
        old = atomicCAS(addr, assumed, newv);
    } while (old != assumed);
#endif
}

// ---------- GEMM: C[M,N] = A[M,K](bf16) * B[N,K]^T(bf16) + bias, fp32 out ----------
// 128x128 tile, BK=64, 256 threads = 4 waves in 2x2, each wave 64x64 via 4x4 MFMA 16x16x32.
// LDS layout: tile row r (0..127) occupies 128 B; 16B chunk c of the row is stored at
// position c ^ (r&7)  -> fragment reads are 2-way bank-aliased (free), staging DMA linear.
__global__ __launch_bounds__(256) void gemm_bt_bias(
    const unsigned short* __restrict__ A,   // [M_TOK][KF] bf16
    const unsigned short* __restrict__ B,   // [NF][KF] bf16
    const float* __restrict__ bias,
    float* __restrict__ C)
{
    __shared__ unsigned short As[128 * BK];   // 16 KB
    __shared__ unsigned short Bs[128 * BK];   // 16 KB

    const int tid  = threadIdx.x;
    const int lane = tid & 63;
    const int wave = tid >> 6;
    const int wm   = wave >> 1;   // 0..1
    const int wn   = wave & 1;    // 0..1
    const int bm   = blockIdx.x;  // 0..63
    const int bn   = blockIdx.y;  // 0..31

    f32x4 acc[4][4] = {};

    // ---- staging addressing (each wave stages 32 rows of A and B via 4 instrs of 8 rows) ----
    const int lr8 = lane >> 3;          // row within 8-row group (0..7)
    const int lp  = lane & 7;           // LDS chunk position within 128B row
    const int gc  = lp ^ lr8;           // swizzle: global chunk fetched into position lp

    const unsigned short* gA[4];
    const unsigned short* gB[4];
#pragma unroll
    for (int t = 0; t < 4; ++t) {
        int r = wave * 32 + t * 8 + lr8;            // tile-local row
        gA[t] = A + (size_t)(bm * 128 + r) * KF + gc * 8;
        gB[t] = B + (size_t)(bn * 128 + r) * KF + gc * 8;
    }
    unsigned short* lA[4];
    unsigned short* lB[4];
#pragma unroll
    for (int t = 0; t < 4; ++t) {
        lA[t] = &As[(wave * 32 + t * 8) * BK];
        lB[t] = &Bs[(wave * 32 + t * 8) * BK];
    }

    // ---- fragment read offsets (constant through the K loop) ----
    // A-frag for 16x16x32 MFMA: lane holds [m = lane&15][k = (lane>>4)*8 + j]
    const int fr   = lane & 15;
    const int quad = lane >> 4;
    int offA[4][2], offB[4][2];
#pragma unroll
    for (int i = 0; i < 4; ++i) {
        int rA = wm * 64 + i * 16 + fr;
        int rB = wn * 64 + i * 16 + fr;
#pragma unroll
        for (int s = 0; s < 2; ++s) {
            int c = s * 4 + quad;                       // 16B chunk index within row
            offA[i][s] = rA * BK + ((c ^ (rA & 7)) * 8);
            offB[i][s] = rB * BK + ((c ^ (rB & 7)) * 8);
        }
    }

    for (int k0 = 0; k0 < KF; k0 += BK) {
        __syncthreads();   // protect LDS from previous iteration's readers
#pragma unroll
        for (int t = 0; t < 4; ++t) load_lds16(gA[t], lA[t]);
#pragma unroll
        for (int t = 0; t < 4; ++t) load_lds16(gB[t], lB[t]);
#pragma unroll
        for (int t = 0; t < 4; ++t) { gA[t] += BK; gB[t] += BK; }
        __syncthreads();   // drain staging for all waves

#pragma unroll
        for (int s = 0; s < 2; ++s) {
            bf16x8 af[4], bfr[4];
#pragma unroll
            for (int i = 0; i < 4; ++i) af[i]  = *(const bf16x8*)&As[offA[i][s]];
#pragma unroll
            for (int j = 0; j < 4; ++j) bfr[j] = *(const bf16x8*)&Bs[offB[j][s]];
#pragma unroll
            for (int i = 0; i < 4; ++i)
#pragma unroll
                for (int j = 0; j < 4; ++j)
                    acc[i][j] = __builtin_amdgcn_mfma_f32_16x16x32_bf16(af[i], bfr[j], acc[i][j], 0, 0, 0);
        }
    }

    // epilogue: C/D layout col = lane&15, row = (lane>>4)*4 + reg
    const int crow = bm * 128 + wm * 64;
    const int ccol = bn * 128 + wn * 64;
    const int c_l  = lane & 15;
    const int r_l  = (lane >> 4) * 4;
#pragma unroll
    for (int j = 0; j < 4; ++j) {
        int col = ccol + j * 16 + c_l;
        float bv = bias[col];
#pragma unroll
        for (int i = 0; i < 4; ++i) {
#pragma unroll
            for (int r = 0; r < 4; ++r)
                C[(size_t)(crow + i * 16 + r_l + r) * NF + col] = acc[i][j][r] + bv;
        }
    }
}

// ---------- launch ----------
extern "C" void kernel_launch(void* const* d_in, const int* in_sizes, int n_in,
                              void* d_out, int out_size, void* d_ws, size_t ws_size,
                              hipStream_t stream) {
    const float* x    = (const float*)d_in[0];
    const float* w    = (const float*)d_in[1];
    const float* bias = (const float*)d_in[2];
    const int*   idx  = (const int*)d_in[3];
    float* out = (float*)d_out;
    const int nnz = in_sizes[1];

    // Scratch layout in ws:
    //  - ws + 0      : W bf16  (32MB)  -- scattered into directly (no fp32 intermediate)
    //  - ws + 32MB   : X bf16  (64MB)
    unsigned short* Wb = (unsigned short*)d_ws;
    unsigned short* Xb = (unsigned short*)((char*)d_ws + (size_t)NF * KF * sizeof(unsigned short));

    const int nx4 = M_TOK * KF / 4;           // X in float4 units (8.39M)
    const int nwb = NF * KF * 2 / 16;         // W bf16 in uint4 units (2.10M)

    // 1) fused: zero bf16 W + convert X -> bf16
    prep_zero_convx<<<(nx4 + 255) / 256, 256, 0, stream>>>(
        (const float4*)x, (ushort4*)Xb, (uint4*)Wb, nx4, nwb);
    // 2) scatter COO straight into bf16 W (duplicates sum via packed-bf16 atomics)
    scatter_bf16<<<(nnz + 255) / 256, 256, 0, stream>>>(idx, w, Wb, nnz);
    // 3) GEMM + bias (overwrites all of d_out)
    gemm_bt_bias<<<dim3(M_TOK / 128, NF / 128), 256, 0, stream>>>(Xb, Wb, bias, out);
}